// Round 6
// baseline (248.045 us; speedup 1.0000x reference)
//
#include <hip/hip_runtime.h>
#include <hip/hip_bf16.h>

#define N 4096
#define D 128
#define NB2 4096         // bins for lms (12-bit key; bin == key)
#define T3 1024          // threads for lms kernel
#define EPT (N / T3)     // 4 elements per thread
#define BPT2 (NB2 / T3)  // 4 bins per thread
#define NW (T3 / 64)     // 16 waves

#define ESCALE 33554432.0f          // 2^25 fixed-point scale for e-histogram
#define EINV   (1.0f / 33554432.0f)

static constexpr size_t WS_ACC_OFF = 0;        // double acc[2]
static constexpr size_t WS_X2_OFF  = 64;       // float x2[N] (16 KB)
static constexpr size_t WS_FBF_OFF = 16448;    // bf16 fbf[N*D] (1 MB)
static constexpr size_t WS_E_NEW   = 1065024;  // bf16 E[N*N]
static constexpr size_t WS_E_OLD   = 32768;    // legacy layout (no fbf)
static constexpr size_t WS_NEED_NEW = WS_E_NEW + (size_t)N * N * 2;

typedef __attribute__((ext_vector_type(8))) short short8;   // 8 bf16 (4 VGPRs)
typedef __attribute__((ext_vector_type(4))) float f32x4;    // MFMA C/D

__device__ inline unsigned short f2bf(float x) {
    __hip_bfloat16 h = __float2bfloat16(x);
    return *(unsigned short*)&h;
}

// ---------------- kernel 1: row squared norms (fp32 exact) + optional bf16 copy ----------------
__global__ void x2_kernel(const float* __restrict__ f, float* __restrict__ x2,
                          unsigned short* __restrict__ fbf) {
    int row = blockIdx.x;
    int t = threadIdx.x;
    float a = f[row * D + t];
    float b = f[row * D + t + 64];
    if (fbf) {
        fbf[row * D + t] = f2bf(a);
        fbf[row * D + t + 64] = f2bf(b);
    }
    float v = a * a + b * b;
    #pragma unroll
    for (int off = 32; off > 0; off >>= 1) v += __shfl_down(v, off);
    if (t == 0) x2[row] = v;
}

// ---------------- kernel 2 (new): Gram via bf16 MFMA from PRE-CONVERTED bf16 ----------------
// No converts in the K-loop; 16B staging loads; no min-wave clamp (avoid VGPR spill).
__global__ __launch_bounds__(256) void gram_fbf(const unsigned short* __restrict__ fbf,
                                                const float* __restrict__ x2,
                                                __hip_bfloat16* __restrict__ E,
                                                double* __restrict__ acc) {
    __shared__ __align__(16) unsigned short smem[2 * 128 * 72];
    __shared__ float waveRed[4];
    unsigned short* As = smem;
    unsigned short* Bs = smem + 128 * 72;

    int tid = threadIdx.x;
    int lane = tid & 63;
    int wave = tid >> 6;
    int wr = wave >> 1, wc = wave & 1;
    int rowBase = blockIdx.y * 128, colBase = blockIdx.x * 128;

    f32x4 accv[4][4];
    #pragma unroll
    for (int i = 0; i < 4; i++)
        #pragma unroll
        for (int j = 0; j < 4; j++) accv[i][j] = (f32x4){0.f, 0.f, 0.f, 0.f};

    int col = lane & 15;
    int quad = lane >> 4;

    for (int kc = 0; kc < D; kc += 64) {
        __syncthreads();
        // stage 128x64 bf16 per panel: 1024 16B-chunks / 256 thr = 4 insts/panel
        #pragma unroll
        for (int it = 0; it < 4; it++) {
            int lin = tid + it * 256;
            int m = lin >> 3;            // 8 chunks of 8 shorts per row
            int c8 = lin & 7;
            uint4 va = *(const uint4*)&fbf[(size_t)(rowBase + m) * D + kc + c8 * 8];
            uint4 vb = *(const uint4*)&fbf[(size_t)(colBase + m) * D + kc + c8 * 8];
            *(uint4*)&As[m * 72 + c8 * 8] = va;
            *(uint4*)&Bs[m * 72 + c8 * 8] = vb;
        }
        __syncthreads();

        #pragma unroll
        for (int c = 0; c < 2; c++) {
            int k = c * 32 + quad * 8;
            short8 af[4], bf[4];
            #pragma unroll
            for (int i = 0; i < 4; i++)
                af[i] = *(const short8*)&As[(wr * 64 + i * 16 + col) * 72 + k];
            #pragma unroll
            for (int j = 0; j < 4; j++)
                bf[j] = *(const short8*)&Bs[(wc * 64 + j * 16 + col) * 72 + k];
            #pragma unroll
            for (int i = 0; i < 4; i++)
                #pragma unroll
                for (int j = 0; j < 4; j++)
                    accv[i][j] = __builtin_amdgcn_mfma_f32_16x16x32_bf16(
                        af[i], bf[j], accv[i][j], 0, 0, 0);
        }
    }

    float x2j[4];
    #pragma unroll
    for (int j = 0; j < 4; j++) x2j[j] = x2[colBase + wc * 64 + j * 16 + col];

    __syncthreads();   // reuse smem as Ctile[128][136]

    float sumLogit = 0.f;
    #pragma unroll
    for (int i = 0; i < 4; i++) {
        #pragma unroll
        for (int r = 0; r < 4; r++) {
            int lr = wr * 64 + i * 16 + quad * 4 + r;
            int gi = rowBase + lr;
            float x2i = x2[gi];
            #pragma unroll
            for (int j = 0; j < 4; j++) {
                int lc = wc * 64 + j * 16 + col;
                int gj = colBase + lc;
                float sq = x2i + x2j[j] - 2.f * accv[i][j][r];
                sq = fmaxf(sq, 0.f);
                float logit = (sq > 0.f) ? (-0.5f * sqrtf(sq)) : 0.f;
                float e = __expf(logit);
                if (gi == gj) { e = 0.f; logit = 0.f; }
                sumLogit += logit;
                smem[lr * 136 + lc] = f2bf(e);
            }
        }
    }
    __syncthreads();

    #pragma unroll
    for (int it = 0; it < 8; it++) {
        int lin = tid + it * 256;
        int r = lin >> 4;
        int c8 = lin & 15;
        uint4 v = *(const uint4*)&smem[r * 136 + c8 * 8];
        *(uint4*)&E[(size_t)(rowBase + r) * N + colBase + c8 * 8] = v;
    }

    #pragma unroll
    for (int off = 32; off > 0; off >>= 1) sumLogit += __shfl_down(sumLogit, off);
    if (lane == 0) waveRed[wave] = sumLogit;
    __syncthreads();
    if (tid == 0)
        atomicAdd(&acc[0], (double)(waveRed[0] + waveRed[1] + waveRed[2] + waveRed[3]));
}

// ---------------- kernel 2 (legacy fallback, converts fp32 in-loop) ----------------
__global__ __launch_bounds__(256) void gram_legacy(const float* __restrict__ f,
                                                   const float* __restrict__ x2,
                                                   __hip_bfloat16* __restrict__ E,
                                                   double* __restrict__ acc) {
    __shared__ __align__(16) unsigned short smem[2 * 128 * 72];
    __shared__ float waveRed[4];
    unsigned short* As = smem;
    unsigned short* Bs = smem + 128 * 72;

    int tid = threadIdx.x;
    int lane = tid & 63;
    int wave = tid >> 6;
    int wr = wave >> 1, wc = wave & 1;
    int rowBase = blockIdx.y * 128, colBase = blockIdx.x * 128;

    f32x4 accv[4][4];
    #pragma unroll
    for (int i = 0; i < 4; i++)
        #pragma unroll
        for (int j = 0; j < 4; j++) accv[i][j] = (f32x4){0.f, 0.f, 0.f, 0.f};

    int col = lane & 15;
    int quad = lane >> 4;

    for (int kc = 0; kc < D; kc += 64) {
        __syncthreads();
        #pragma unroll
        for (int it = 0; it < 8; it++) {
            int lin = tid + it * 256;
            int m = lin >> 4;
            int f4i = lin & 15;
            float4 va = ((const float4*)f)[(size_t)(rowBase + m) * 32 + (kc >> 2) + f4i];
            float4 vb = ((const float4*)f)[(size_t)(colBase + m) * 32 + (kc >> 2) + f4i];
            ushort4 ua = {f2bf(va.x), f2bf(va.y), f2bf(va.z), f2bf(va.w)};
            ushort4 ub = {f2bf(vb.x), f2bf(vb.y), f2bf(vb.z), f2bf(vb.w)};
            *(ushort4*)&As[m * 72 + f4i * 4] = ua;
            *(ushort4*)&Bs[m * 72 + f4i * 4] = ub;
        }
        __syncthreads();

        #pragma unroll
        for (int c = 0; c < 2; c++) {
            int k = c * 32 + quad * 8;
            short8 af[4], bf[4];
            #pragma unroll
            for (int i = 0; i < 4; i++)
                af[i] = *(const short8*)&As[(wr * 64 + i * 16 + col) * 72 + k];
            #pragma unroll
            for (int j = 0; j < 4; j++)
                bf[j] = *(const short8*)&Bs[(wc * 64 + j * 16 + col) * 72 + k];
            #pragma unroll
            for (int i = 0; i < 4; i++)
                #pragma unroll
                for (int j = 0; j < 4; j++)
                    accv[i][j] = __builtin_amdgcn_mfma_f32_16x16x32_bf16(
                        af[i], bf[j], accv[i][j], 0, 0, 0);
        }
    }

    float x2j[4];
    #pragma unroll
    for (int j = 0; j < 4; j++) x2j[j] = x2[colBase + wc * 64 + j * 16 + col];

    __syncthreads();

    float sumLogit = 0.f;
    #pragma unroll
    for (int i = 0; i < 4; i++) {
        #pragma unroll
        for (int r = 0; r < 4; r++) {
            int lr = wr * 64 + i * 16 + quad * 4 + r;
            int gi = rowBase + lr;
            float x2i = x2[gi];
            #pragma unroll
            for (int j = 0; j < 4; j++) {
                int lc = wc * 64 + j * 16 + col;
                int gj = colBase + lc;
                float sq = x2i + x2j[j] - 2.f * accv[i][j][r];
                sq = fmaxf(sq, 0.f);
                float logit = (sq > 0.f) ? (-0.5f * sqrtf(sq)) : 0.f;
                float e = __expf(logit);
                if (gi == gj) { e = 0.f; logit = 0.f; }
                sumLogit += logit;
                smem[lr * 136 + lc] = f2bf(e);
            }
        }
    }
    __syncthreads();

    #pragma unroll
    for (int it = 0; it < 8; it++) {
        int lin = tid + it * 256;
        int r = lin >> 4;
        int c8 = lin & 15;
        uint4 v = *(const uint4*)&smem[r * 136 + c8 * 8];
        *(uint4*)&E[(size_t)(rowBase + r) * N + colBase + c8 * 8] = v;
    }

    #pragma unroll
    for (int off = 32; off > 0; off >>= 1) sumLogit += __shfl_down(sumLogit, off);
    if (lane == 0) waveRed[wave] = sumLogit;
    __syncthreads();
    if (tid == 0)
        atomicAdd(&acc[0], (double)(waveRed[0] + waveRed[1] + waveRed[2] + waveRed[3]));
}

// ---------------- kernel 3: per-(row,matrix) histogram-suffix masked log-sum ----------------
// grid = (N, 2), 1024 threads (EPT=4): short critical path. Fixed-point e-histogram
// via native ds_add_u32, float suffix scan over 4096 bins, S_k = hsum[key_k].
__global__ __launch_bounds__(T3, 8) void lms_kernel(const __hip_bfloat16* __restrict__ E,
                                                    const float* __restrict__ theta,
                                                    const float* __restrict__ shift,
                                                    double* __restrict__ acc) {
    __shared__ __align__(16) unsigned histu[NB2];   // 16 KB; floats after scan
    __shared__ float waveTot[NW];
    __shared__ float waveRed[NW];
    float* histf = (float*)histu;

    int tid = threadIdx.x;
    int lane = tid & 63;
    int wave = tid >> 6;
    int row = blockIdx.x;
    const float* dmat = blockIdx.y ? shift : theta;
    float kscale = blockIdx.y ? ((float)NB2 / 100.0f) : ((float)NB2 / 180.0f);

    // zero bins
    #pragma unroll
    for (int q = 0; q < BPT2; q++) histu[tid + q * T3] = 0u;

    // load 4 d + 4 e (this thread's elements are j = tid*4 + q)
    unsigned key[EPT];
    unsigned eu[EPT];
    {
        float4 v = ((const float4*)&dmat[(size_t)row * N])[tid];
        uint2 e2 = ((const uint2*)&E[(size_t)row * N])[tid];
        float dv[4] = {v.x, v.y, v.z, v.w};
        unsigned eb[4] = {e2.x << 16, e2.x & 0xffff0000u, e2.y << 16, e2.y & 0xffff0000u};
        #pragma unroll
        for (int idx = 0; idx < 4; idx++) {
            int dk = (int)(dv[idx] * kscale);
            key[idx] = (unsigned)min(max(dk, 0), NB2 - 1);
            eu[idx] = (unsigned)__float2uint_rn(__uint_as_float(eb[idx]) * ESCALE);
        }
    }
    __syncthreads();   // bins zeroed

    // 1) histogram e-sums, native integer LDS atomics
    #pragma unroll
    for (int q = 0; q < EPT; q++)
        atomicAdd(&histu[key[q]], eu[q]);
    __syncthreads();

    // 2) inclusive suffix scan over 4096 bins (4 contiguous per thread), in float
    int base = tid * BPT2;
    {
        uint4 b = *(const uint4*)&histu[base];
        float s[BPT2] = {(float)b.x * EINV, (float)b.y * EINV,
                         (float)b.z * EINV, (float)b.w * EINV};
        float t = 0.f;
        #pragma unroll
        for (int q = BPT2 - 1; q >= 0; q--) { t += s[q]; s[q] = t; }
        float incl = t;
        #pragma unroll
        for (int off = 1; off < 64; off <<= 1) {
            float v = __shfl_down(incl, off);
            if (lane + off < 64) incl += v;
        }
        if (lane == 0) waveTot[wave] = incl;
        __syncthreads();
        float beyond = 0.f;
        for (int w = wave + 1; w < NW; w++) beyond += waveTot[w];
        float add = beyond + (incl - t);
        #pragma unroll
        for (int q = 0; q < BPT2; q++) s[q] += add;
        *(float4*)&histf[base] = *(const float4*)&s[0];
    }
    __syncthreads();

    // 3) per-element: S_k = histf[key_k]; accumulate log
    float localSum = 0.f;
    #pragma unroll
    for (int q = 0; q < EPT; q++) {
        int j = tid * 4 + q;
        if (j == row) continue;          // diagonal k dropped
        localSum += __logf(histf[key[q]]);
    }

    #pragma unroll
    for (int off = 32; off > 0; off >>= 1) localSum += __shfl_down(localSum, off);
    if (lane == 0) waveRed[wave] = localSum;
    __syncthreads();
    if (tid == 0) {
        float s = 0.f;
        #pragma unroll
        for (int w = 0; w < NW; w++) s += waveRed[w];
        atomicAdd(&acc[1], (double)s);
    }
}

// ---------------- final: combine ----------------
__global__ void final_kernel(const double* __restrict__ acc, float* __restrict__ out) {
    double denom = (double)N * (double)(N - 1);
    out[0] = (float)(-(acc[0] - 0.5 * acc[1]) / denom);
}

extern "C" void kernel_launch(void* const* d_in, const int* in_sizes, int n_in,
                              void* d_out, int out_size, void* d_ws, size_t ws_size,
                              hipStream_t stream) {
    const float* theta = (const float*)d_in[0];
    const float* shift = (const float*)d_in[1];
    const float* feat  = (const float*)d_in[2];
    float* out = (float*)d_out;

    char* ws = (char*)d_ws;
    double* acc = (double*)(ws + WS_ACC_OFF);
    float* x2 = (float*)(ws + WS_X2_OFF);

    bool big = ws_size >= WS_NEED_NEW;
    __hip_bfloat16* E = (__hip_bfloat16*)(ws + (big ? WS_E_NEW : WS_E_OLD));
    unsigned short* fbf = big ? (unsigned short*)(ws + WS_FBF_OFF) : nullptr;

    hipMemsetAsync(acc, 0, 2 * sizeof(double), stream);
    x2_kernel<<<N, 64, 0, stream>>>(feat, x2, fbf);
    if (big)
        gram_fbf<<<dim3(32, 32), 256, 0, stream>>>(fbf, x2, E, acc);
    else
        gram_legacy<<<dim3(32, 32), 256, 0, stream>>>(feat, x2, E, acc);
    lms_kernel<<<dim3(N, 2), T3, 0, stream>>>(E, theta, shift, acc);
    final_kernel<<<1, 1, 0, stream>>>(acc, out);
}

// Round 7
// 196.908 us; speedup vs baseline: 1.2597x; 1.2597x over previous
//
#include <hip/hip_runtime.h>
#include <hip/hip_bf16.h>

#define N 4096
#define D 128
#define NB2 4096         // bins for lms (12-bit key; bin == key)
#define T3 1024          // threads for lms kernel
#define EPT (N / T3)     // 4 elements per thread
#define BPT2 (NB2 / T3)  // 4 bins per thread
#define NW (T3 / 64)     // 16 waves

#define ESCALE 33554432.0f          // 2^25 fixed-point scale for e-histogram
#define EINV   (1.0f / 33554432.0f)

static constexpr size_t WS_ACC_OFF = 0;        // double acc[2]
static constexpr size_t WS_X2_OFF  = 64;       // float x2[N] (16 KB)
static constexpr size_t WS_FBF_OFF = 16448;    // bf16 fbf[N*D] (1 MB)
static constexpr size_t WS_E_NEW   = 1065024;  // bf16 E[N*N]
static constexpr size_t WS_E_OLD   = 32768;    // legacy layout (no fbf)
static constexpr size_t WS_NEED_NEW = WS_E_NEW + (size_t)N * N * 2;

typedef __attribute__((ext_vector_type(8))) short short8;   // 8 bf16 (4 VGPRs)
typedef __attribute__((ext_vector_type(4))) float f32x4;    // MFMA C/D

__device__ inline unsigned short f2bf(float x) {
    __hip_bfloat16 h = __float2bfloat16(x);
    return *(unsigned short*)&h;
}

// ---------------- kernel 1: row squared norms (fp32 exact) + optional bf16 copy ----------------
__global__ void x2_kernel(const float* __restrict__ f, float* __restrict__ x2,
                          unsigned short* __restrict__ fbf) {
    int row = blockIdx.x;
    int t = threadIdx.x;
    float a = f[row * D + t];
    float b = f[row * D + t + 64];
    if (fbf) {
        fbf[row * D + t] = f2bf(a);
        fbf[row * D + t + 64] = f2bf(b);
    }
    float v = a * a + b * b;
    #pragma unroll
    for (int off = 32; off > 0; off >>= 1) v += __shfl_down(v, off);
    if (t == 0) x2[row] = v;
}

// ---------------- kernel 2: TRIANGULAR Gram via bf16 MFMA ----------------
// G is symmetric: 528 tiles (bi >= bj) instead of 1024. Each block computes one
// 128x128 tile, stores it straight AND transposed (both coalesced via LDS tile),
// and counts off-diagonal logits twice.
template<bool USE_BF>
__global__ __launch_bounds__(256) void gram_tri(const unsigned short* __restrict__ fbf,
                                                const float* __restrict__ f,
                                                const float* __restrict__ x2,
                                                __hip_bfloat16* __restrict__ E,
                                                double* __restrict__ acc) {
    __shared__ __align__(16) unsigned short smem[2 * 128 * 72];  // 36 KB; reused as Ctile[128][136]
    __shared__ float waveRed[4];
    unsigned short* As = smem;
    unsigned short* Bs = smem + 128 * 72;

    int tid = threadIdx.x;
    int lane = tid & 63;
    int wave = tid >> 6;
    int wr = wave >> 1, wc = wave & 1;

    // triangular index: t -> (bi, bj) with bi >= bj
    int t = blockIdx.x;
    int bi = (int)((sqrtf(8.0f * (float)t + 1.0f) - 1.0f) * 0.5f);
    while ((bi + 1) * (bi + 2) / 2 <= t) bi++;
    while (bi * (bi + 1) / 2 > t) bi--;
    int bj = t - bi * (bi + 1) / 2;
    int rowBase = bi * 128, colBase = bj * 128;
    bool offdiag = (bi != bj);

    f32x4 accv[4][4];
    #pragma unroll
    for (int i = 0; i < 4; i++)
        #pragma unroll
        for (int j = 0; j < 4; j++) accv[i][j] = (f32x4){0.f, 0.f, 0.f, 0.f};

    int col = lane & 15;
    int quad = lane >> 4;

    for (int kc = 0; kc < D; kc += 64) {
        __syncthreads();
        if (USE_BF) {
            #pragma unroll
            for (int it = 0; it < 4; it++) {
                int lin = tid + it * 256;
                int m = lin >> 3;            // 8 chunks of 8 shorts per row
                int c8 = lin & 7;
                uint4 va = *(const uint4*)&fbf[(size_t)(rowBase + m) * D + kc + c8 * 8];
                uint4 vb = *(const uint4*)&fbf[(size_t)(colBase + m) * D + kc + c8 * 8];
                *(uint4*)&As[m * 72 + c8 * 8] = va;
                *(uint4*)&Bs[m * 72 + c8 * 8] = vb;
            }
        } else {
            #pragma unroll
            for (int it = 0; it < 8; it++) {
                int lin = tid + it * 256;
                int m = lin >> 4;
                int f4i = lin & 15;
                float4 va = ((const float4*)f)[(size_t)(rowBase + m) * 32 + (kc >> 2) + f4i];
                float4 vb = ((const float4*)f)[(size_t)(colBase + m) * 32 + (kc >> 2) + f4i];
                ushort4 ua = {f2bf(va.x), f2bf(va.y), f2bf(va.z), f2bf(va.w)};
                ushort4 ub = {f2bf(vb.x), f2bf(vb.y), f2bf(vb.z), f2bf(vb.w)};
                *(ushort4*)&As[m * 72 + f4i * 4] = ua;
                *(ushort4*)&Bs[m * 72 + f4i * 4] = ub;
            }
        }
        __syncthreads();

        #pragma unroll
        for (int c = 0; c < 2; c++) {
            int k = c * 32 + quad * 8;
            short8 af[4], bf[4];
            #pragma unroll
            for (int i = 0; i < 4; i++)
                af[i] = *(const short8*)&As[(wr * 64 + i * 16 + col) * 72 + k];
            #pragma unroll
            for (int j = 0; j < 4; j++)
                bf[j] = *(const short8*)&Bs[(wc * 64 + j * 16 + col) * 72 + k];
            #pragma unroll
            for (int i = 0; i < 4; i++)
                #pragma unroll
                for (int j = 0; j < 4; j++)
                    accv[i][j] = __builtin_amdgcn_mfma_f32_16x16x32_bf16(
                        af[i], bf[j], accv[i][j], 0, 0, 0);
        }
    }

    float x2j[4];
    #pragma unroll
    for (int j = 0; j < 4; j++) x2j[j] = x2[colBase + wc * 64 + j * 16 + col];

    // compute e (packed bf16 pairs in regs) + logit sum
    unsigned epk[4][4][2];
    float sumLogit = 0.f;
    #pragma unroll
    for (int i = 0; i < 4; i++) {
        float x2iv[4];
        #pragma unroll
        for (int r = 0; r < 4; r++)
            x2iv[r] = x2[rowBase + wr * 64 + i * 16 + quad * 4 + r];
        #pragma unroll
        for (int j = 0; j < 4; j++) {
            unsigned p0 = 0, p1 = 0;
            #pragma unroll
            for (int r = 0; r < 4; r++) {
                int gi = rowBase + wr * 64 + i * 16 + quad * 4 + r;
                int gj = colBase + wc * 64 + j * 16 + col;
                float sq = x2iv[r] + x2j[j] - 2.f * accv[i][j][r];
                sq = fmaxf(sq, 0.f);
                float logit = (sq > 0.f) ? (-0.5f * sqrtf(sq)) : 0.f;
                float e = __expf(logit);
                if (gi == gj) { e = 0.f; logit = 0.f; }
                sumLogit += logit;
                unsigned hb = (unsigned)f2bf(e);
                if (r < 2) p0 |= hb << (16 * r); else p1 |= hb << (16 * (r - 2));
            }
            epk[i][j][0] = p0; epk[i][j][1] = p1;
        }
    }
    if (offdiag) sumLogit *= 2.f;   // (i,j) and (j,i) both contribute; dist symmetric

    // phase A: straight tile through LDS, coalesced store
    __syncthreads();   // done reading As/Bs
    #pragma unroll
    for (int i = 0; i < 4; i++)
        #pragma unroll
        for (int j = 0; j < 4; j++)
            #pragma unroll
            for (int r = 0; r < 4; r++) {
                int lr = wr * 64 + i * 16 + quad * 4 + r;
                int lc = wc * 64 + j * 16 + col;
                smem[lr * 136 + lc] = (unsigned short)(epk[i][j][r >> 1] >> (16 * (r & 1)));
            }
    __syncthreads();
    #pragma unroll
    for (int it = 0; it < 8; it++) {
        int lin = tid + it * 256;
        int r = lin >> 4;
        int c8 = lin & 15;
        uint4 v = *(const uint4*)&smem[r * 136 + c8 * 8];
        *(uint4*)&E[(size_t)(rowBase + r) * N + colBase + c8 * 8] = v;
    }

    // phase B: transposed tile (only off-diagonal blocks; block-uniform branch)
    if (offdiag) {
        __syncthreads();   // straight-store LDS reads done
        #pragma unroll
        for (int i = 0; i < 4; i++)
            #pragma unroll
            for (int j = 0; j < 4; j++)
                #pragma unroll
                for (int r = 0; r < 4; r++) {
                    int lr = wr * 64 + i * 16 + quad * 4 + r;
                    int lc = wc * 64 + j * 16 + col;
                    smem[lc * 136 + lr] = (unsigned short)(epk[i][j][r >> 1] >> (16 * (r & 1)));
                }
        __syncthreads();
        #pragma unroll
        for (int it = 0; it < 8; it++) {
            int lin = tid + it * 256;
            int r = lin >> 4;
            int c8 = lin & 15;
            uint4 v = *(const uint4*)&smem[r * 136 + c8 * 8];
            *(uint4*)&E[(size_t)(colBase + r) * N + rowBase + c8 * 8] = v;
        }
    }

    #pragma unroll
    for (int off = 32; off > 0; off >>= 1) sumLogit += __shfl_down(sumLogit, off);
    if (lane == 0) waveRed[wave] = sumLogit;
    __syncthreads();
    if (tid == 0)
        atomicAdd(&acc[0], (double)(waveRed[0] + waveRed[1] + waveRed[2] + waveRed[3]));
}

// ---------------- kernel 3: fused per-row masked log-sums (theta AND shift) ----------------
// grid = N, 1024 threads. E/theta/shift rows loaded up-front (one latency exposure,
// E read once). Per pass: fixed-point e-histogram via native ds_add_u32, float
// suffix scan over 4096 bins, gather S_k = hsum[key_k].
__device__ __forceinline__ float lms_pass(const unsigned* key, const unsigned* eu,
                                          unsigned* histu, float* waveTot,
                                          int tid, int lane, int wave, int row) {
    float* histf = (float*)histu;
    __syncthreads();   // previous pass's gather reads done
    #pragma unroll
    for (int q = 0; q < BPT2; q++) histu[tid + q * T3] = 0u;
    __syncthreads();

    #pragma unroll
    for (int q = 0; q < EPT; q++)
        atomicAdd(&histu[key[q]], eu[q]);
    __syncthreads();

    int base = tid * BPT2;
    {
        uint4 b = *(const uint4*)&histu[base];
        float s[BPT2] = {(float)b.x * EINV, (float)b.y * EINV,
                         (float)b.z * EINV, (float)b.w * EINV};
        float t = 0.f;
        #pragma unroll
        for (int q = BPT2 - 1; q >= 0; q--) { t += s[q]; s[q] = t; }
        float incl = t;
        #pragma unroll
        for (int off = 1; off < 64; off <<= 1) {
            float v = __shfl_down(incl, off);
            if (lane + off < 64) incl += v;
        }
        if (lane == 0) waveTot[wave] = incl;
        __syncthreads();
        float beyond = 0.f;
        for (int w = wave + 1; w < NW; w++) beyond += waveTot[w];
        float add = beyond + (incl - t);
        #pragma unroll
        for (int q = 0; q < BPT2; q++) s[q] += add;
        *(float4*)&histf[base] = *(const float4*)&s[0];
    }
    __syncthreads();

    float ls = 0.f;
    #pragma unroll
    for (int q = 0; q < EPT; q++) {
        int j = tid * EPT + q;
        if (j == row) continue;          // diagonal k dropped
        ls += __logf(histf[key[q]]);
    }
    return ls;
}

__global__ __launch_bounds__(T3) void lms_kernel(const __hip_bfloat16* __restrict__ E,
                                                 const float* __restrict__ theta,
                                                 const float* __restrict__ shift,
                                                 double* __restrict__ acc) {
    __shared__ __align__(16) unsigned histu[NB2];   // 16 KB; floats after scan
    __shared__ float waveTot[NW];
    __shared__ float waveRed[NW];

    int tid = threadIdx.x;
    int lane = tid & 63;
    int wave = tid >> 6;
    int row = blockIdx.x;

    // all three row-loads issued together: one latency exposure, E read once
    float4 tv = ((const float4*)&theta[(size_t)row * N])[tid];
    float4 sv = ((const float4*)&shift[(size_t)row * N])[tid];
    uint2 e2 = ((const uint2*)&E[(size_t)row * N])[tid];

    unsigned eu[EPT];
    unsigned keyT[EPT], keyS[EPT];
    {
        unsigned eb[4] = {e2.x << 16, e2.x & 0xffff0000u, e2.y << 16, e2.y & 0xffff0000u};
        float tdv[4] = {tv.x, tv.y, tv.z, tv.w};
        float sdv[4] = {sv.x, sv.y, sv.z, sv.w};
        const float ksT = (float)NB2 / 180.0f;
        const float ksS = (float)NB2 / 100.0f;
        #pragma unroll
        for (int idx = 0; idx < 4; idx++) {
            eu[idx] = (unsigned)__float2uint_rn(__uint_as_float(eb[idx]) * ESCALE);
            keyT[idx] = (unsigned)min(max((int)(tdv[idx] * ksT), 0), NB2 - 1);
            keyS[idx] = (unsigned)min(max((int)(sdv[idx] * ksS), 0), NB2 - 1);
        }
    }

    float localSum = lms_pass(keyT, eu, histu, waveTot, tid, lane, wave, row)
                   + lms_pass(keyS, eu, histu, waveTot, tid, lane, wave, row);

    #pragma unroll
    for (int off = 32; off > 0; off >>= 1) localSum += __shfl_down(localSum, off);
    if (lane == 0) waveRed[wave] = localSum;
    __syncthreads();
    if (tid == 0) {
        float s = 0.f;
        #pragma unroll
        for (int w = 0; w < NW; w++) s += waveRed[w];
        atomicAdd(&acc[1], (double)s);
    }
}

// ---------------- final: combine ----------------
__global__ void final_kernel(const double* __restrict__ acc, float* __restrict__ out) {
    double denom = (double)N * (double)(N - 1);
    out[0] = (float)(-(acc[0] - 0.5 * acc[1]) / denom);
}

extern "C" void kernel_launch(void* const* d_in, const int* in_sizes, int n_in,
                              void* d_out, int out_size, void* d_ws, size_t ws_size,
                              hipStream_t stream) {
    const float* theta = (const float*)d_in[0];
    const float* shift = (const float*)d_in[1];
    const float* feat  = (const float*)d_in[2];
    float* out = (float*)d_out;

    char* ws = (char*)d_ws;
    double* acc = (double*)(ws + WS_ACC_OFF);
    float* x2 = (float*)(ws + WS_X2_OFF);

    bool big = ws_size >= WS_NEED_NEW;
    __hip_bfloat16* E = (__hip_bfloat16*)(ws + (big ? WS_E_NEW : WS_E_OLD));
    unsigned short* fbf = big ? (unsigned short*)(ws + WS_FBF_OFF) : nullptr;

    const int NTRI = (32 * 33) / 2;   // 528 lower-triangular 128x128 tiles

    hipMemsetAsync(acc, 0, 2 * sizeof(double), stream);
    x2_kernel<<<N, 64, 0, stream>>>(feat, x2, fbf);
    if (big)
        gram_tri<true><<<NTRI, 256, 0, stream>>>(fbf, feat, x2, E, acc);
    else
        gram_tri<false><<<NTRI, 256, 0, stream>>>(nullptr, feat, x2, E, acc);
    lms_kernel<<<N, T3, 0, stream>>>(E, theta, shift, acc);
    final_kernel<<<1, 1, 0, stream>>>(acc, out);
}

// Round 8
// 195.446 us; speedup vs baseline: 1.2691x; 1.0075x over previous
//
#include <hip/hip_runtime.h>
#include <hip/hip_bf16.h>

#define N 4096
#define D 128
#define NB2 4096         // bins for lms (12-bit key; bin == key)
#define T3 1024          // threads for lms kernel
#define NW (T3 / 64)     // 16 waves

#define ESCALE 33554432.0f          // 2^25 fixed-point scale for e-histogram
#define EINV   (1.0f / 33554432.0f)

static constexpr size_t WS_ACC_OFF = 0;        // double acc[2]
static constexpr size_t WS_X2_OFF  = 64;       // float x2[N] (16 KB)
static constexpr size_t WS_FBF_OFF = 16448;    // bf16 fbf[N*D] (1 MB)
static constexpr size_t WS_E_NEW   = 1065024;  // bf16 E[N*N]
static constexpr size_t WS_E_OLD   = 32768;    // legacy layout (no fbf)
static constexpr size_t WS_NEED_NEW = WS_E_NEW + (size_t)N * N * 2;

typedef __attribute__((ext_vector_type(8))) short short8;   // 8 bf16 (4 VGPRs)
typedef __attribute__((ext_vector_type(4))) float f32x4;    // MFMA C/D

__device__ inline unsigned short f2bf(float x) {
    __hip_bfloat16 h = __float2bfloat16(x);
    return *(unsigned short*)&h;
}

// ---------------- kernel 1: row squared norms (fp32 exact) + optional bf16 copy ----------------
__global__ void x2_kernel(const float* __restrict__ f, float* __restrict__ x2,
                          unsigned short* __restrict__ fbf) {
    int row = blockIdx.x;
    int t = threadIdx.x;
    float a = f[row * D + t];
    float b = f[row * D + t + 64];
    if (fbf) {
        fbf[row * D + t] = f2bf(a);
        fbf[row * D + t + 64] = f2bf(b);
    }
    float v = a * a + b * b;
    #pragma unroll
    for (int off = 32; off > 0; off >>= 1) v += __shfl_down(v, off);
    if (t == 0) x2[row] = v;
}

// ---------------- kernel 2: TRIANGULAR Gram via bf16 MFMA (unchanged from R7) ----------------
template<bool USE_BF>
__global__ __launch_bounds__(256) void gram_tri(const unsigned short* __restrict__ fbf,
                                                const float* __restrict__ f,
                                                const float* __restrict__ x2,
                                                __hip_bfloat16* __restrict__ E,
                                                double* __restrict__ acc) {
    __shared__ __align__(16) unsigned short smem[2 * 128 * 72];  // 36 KB; reused as Ctile[128][136]
    __shared__ float waveRed[4];
    unsigned short* As = smem;
    unsigned short* Bs = smem + 128 * 72;

    int tid = threadIdx.x;
    int lane = tid & 63;
    int wave = tid >> 6;
    int wr = wave >> 1, wc = wave & 1;

    int t = blockIdx.x;
    int bi = (int)((sqrtf(8.0f * (float)t + 1.0f) - 1.0f) * 0.5f);
    while ((bi + 1) * (bi + 2) / 2 <= t) bi++;
    while (bi * (bi + 1) / 2 > t) bi--;
    int bj = t - bi * (bi + 1) / 2;
    int rowBase = bi * 128, colBase = bj * 128;
    bool offdiag = (bi != bj);

    f32x4 accv[4][4];
    #pragma unroll
    for (int i = 0; i < 4; i++)
        #pragma unroll
        for (int j = 0; j < 4; j++) accv[i][j] = (f32x4){0.f, 0.f, 0.f, 0.f};

    int col = lane & 15;
    int quad = lane >> 4;

    for (int kc = 0; kc < D; kc += 64) {
        __syncthreads();
        if (USE_BF) {
            #pragma unroll
            for (int it = 0; it < 4; it++) {
                int lin = tid + it * 256;
                int m = lin >> 3;
                int c8 = lin & 7;
                uint4 va = *(const uint4*)&fbf[(size_t)(rowBase + m) * D + kc + c8 * 8];
                uint4 vb = *(const uint4*)&fbf[(size_t)(colBase + m) * D + kc + c8 * 8];
                *(uint4*)&As[m * 72 + c8 * 8] = va;
                *(uint4*)&Bs[m * 72 + c8 * 8] = vb;
            }
        } else {
            #pragma unroll
            for (int it = 0; it < 8; it++) {
                int lin = tid + it * 256;
                int m = lin >> 4;
                int f4i = lin & 15;
                float4 va = ((const float4*)f)[(size_t)(rowBase + m) * 32 + (kc >> 2) + f4i];
                float4 vb = ((const float4*)f)[(size_t)(colBase + m) * 32 + (kc >> 2) + f4i];
                ushort4 ua = {f2bf(va.x), f2bf(va.y), f2bf(va.z), f2bf(va.w)};
                ushort4 ub = {f2bf(vb.x), f2bf(vb.y), f2bf(vb.z), f2bf(vb.w)};
                *(ushort4*)&As[m * 72 + f4i * 4] = ua;
                *(ushort4*)&Bs[m * 72 + f4i * 4] = ub;
            }
        }
        __syncthreads();

        #pragma unroll
        for (int c = 0; c < 2; c++) {
            int k = c * 32 + quad * 8;
            short8 af[4], bf[4];
            #pragma unroll
            for (int i = 0; i < 4; i++)
                af[i] = *(const short8*)&As[(wr * 64 + i * 16 + col) * 72 + k];
            #pragma unroll
            for (int j = 0; j < 4; j++)
                bf[j] = *(const short8*)&Bs[(wc * 64 + j * 16 + col) * 72 + k];
            #pragma unroll
            for (int i = 0; i < 4; i++)
                #pragma unroll
                for (int j = 0; j < 4; j++)
                    accv[i][j] = __builtin_amdgcn_mfma_f32_16x16x32_bf16(
                        af[i], bf[j], accv[i][j], 0, 0, 0);
        }
    }

    float x2j[4];
    #pragma unroll
    for (int j = 0; j < 4; j++) x2j[j] = x2[colBase + wc * 64 + j * 16 + col];

    unsigned epk[4][4][2];
    float sumLogit = 0.f;
    #pragma unroll
    for (int i = 0; i < 4; i++) {
        float x2iv[4];
        #pragma unroll
        for (int r = 0; r < 4; r++)
            x2iv[r] = x2[rowBase + wr * 64 + i * 16 + quad * 4 + r];
        #pragma unroll
        for (int j = 0; j < 4; j++) {
            unsigned p0 = 0, p1 = 0;
            #pragma unroll
            for (int r = 0; r < 4; r++) {
                int gi = rowBase + wr * 64 + i * 16 + quad * 4 + r;
                int gj = colBase + wc * 64 + j * 16 + col;
                float sq = x2iv[r] + x2j[j] - 2.f * accv[i][j][r];
                sq = fmaxf(sq, 0.f);
                float logit = (sq > 0.f) ? (-0.5f * sqrtf(sq)) : 0.f;
                float e = __expf(logit);
                if (gi == gj) { e = 0.f; logit = 0.f; }
                sumLogit += logit;
                unsigned hb = (unsigned)f2bf(e);
                if (r < 2) p0 |= hb << (16 * r); else p1 |= hb << (16 * (r - 2));
            }
            epk[i][j][0] = p0; epk[i][j][1] = p1;
        }
    }
    if (offdiag) sumLogit *= 2.f;

    __syncthreads();
    #pragma unroll
    for (int i = 0; i < 4; i++)
        #pragma unroll
        for (int j = 0; j < 4; j++)
            #pragma unroll
            for (int r = 0; r < 4; r++) {
                int lr = wr * 64 + i * 16 + quad * 4 + r;
                int lc = wc * 64 + j * 16 + col;
                smem[lr * 136 + lc] = (unsigned short)(epk[i][j][r >> 1] >> (16 * (r & 1)));
            }
    __syncthreads();
    #pragma unroll
    for (int it = 0; it < 8; it++) {
        int lin = tid + it * 256;
        int r = lin >> 4;
        int c8 = lin & 15;
        uint4 v = *(const uint4*)&smem[r * 136 + c8 * 8];
        *(uint4*)&E[(size_t)(rowBase + r) * N + colBase + c8 * 8] = v;
    }

    if (offdiag) {
        __syncthreads();
        #pragma unroll
        for (int i = 0; i < 4; i++)
            #pragma unroll
            for (int j = 0; j < 4; j++)
                #pragma unroll
                for (int r = 0; r < 4; r++) {
                    int lr = wr * 64 + i * 16 + quad * 4 + r;
                    int lc = wc * 64 + j * 16 + col;
                    smem[lc * 136 + lr] = (unsigned short)(epk[i][j][r >> 1] >> (16 * (r & 1)));
                }
        __syncthreads();
        #pragma unroll
        for (int it = 0; it < 8; it++) {
            int lin = tid + it * 256;
            int r = lin >> 4;
            int c8 = lin & 15;
            uint4 v = *(const uint4*)&smem[r * 136 + c8 * 8];
            *(uint4*)&E[(size_t)(colBase + r) * N + rowBase + c8 * 8] = v;
        }
    }

    #pragma unroll
    for (int off = 32; off > 0; off >>= 1) sumLogit += __shfl_down(sumLogit, off);
    if (lane == 0) waveRed[wave] = sumLogit;
    __syncthreads();
    if (tid == 0)
        atomicAdd(&acc[0], (double)(waveRed[0] + waveRed[1] + waveRed[2] + waveRed[3]));
}

// ---------------- kernel 3: 2 rows per block, fused theta+shift, dual histograms ----------------
// grid = 1024 blocks per dispatch (rows [rowBase, rowBase+2048) as pairs).
// 4 barriers per pass serve TWO rows; VGPR<=64 -> 2 blocks/CU (32 waves).
__device__ __forceinline__ float lms_pass2(const unsigned* k0, const unsigned* k1,
                                           const unsigned* eu0, const unsigned* eu1,
                                           unsigned* h0, unsigned* h1,
                                           float* wT0, float* wT1,
                                           int tid, int lane, int wave, int r0, int r1) {
    float* f0 = (float*)h0;
    float* f1 = (float*)h1;
    __syncthreads();   // previous pass's gather reads done
    #pragma unroll
    for (int q = 0; q < 4; q++) { h0[tid + q * T3] = 0u; h1[tid + q * T3] = 0u; }
    __syncthreads();

    #pragma unroll
    for (int q = 0; q < 4; q++) atomicAdd(&h0[k0[q]], eu0[q]);
    #pragma unroll
    for (int q = 0; q < 4; q++) atomicAdd(&h1[k1[q]], eu1[q]);
    __syncthreads();

    int base = tid * 4;
    uint4 b0 = *(const uint4*)&h0[base];
    uint4 b1 = *(const uint4*)&h1[base];
    float s0[4] = {(float)b0.x * EINV, (float)b0.y * EINV, (float)b0.z * EINV, (float)b0.w * EINV};
    float s1[4] = {(float)b1.x * EINV, (float)b1.y * EINV, (float)b1.z * EINV, (float)b1.w * EINV};
    float t0 = 0.f, t1 = 0.f;
    #pragma unroll
    for (int q = 3; q >= 0; q--) { t0 += s0[q]; s0[q] = t0; t1 += s1[q]; s1[q] = t1; }
    float i0 = t0, i1 = t1;
    #pragma unroll
    for (int off = 1; off < 64; off <<= 1) {
        float v0 = __shfl_down(i0, off);
        float v1 = __shfl_down(i1, off);
        if (lane + off < 64) { i0 += v0; i1 += v1; }
    }
    if (lane == 0) { wT0[wave] = i0; wT1[wave] = i1; }
    __syncthreads();
    float by0 = 0.f, by1 = 0.f;
    for (int w = wave + 1; w < NW; w++) { by0 += wT0[w]; by1 += wT1[w]; }
    float a0 = by0 + (i0 - t0);
    float a1 = by1 + (i1 - t1);
    #pragma unroll
    for (int q = 0; q < 4; q++) { s0[q] += a0; s1[q] += a1; }
    *(float4*)&f0[base] = *(const float4*)&s0[0];
    *(float4*)&f1[base] = *(const float4*)&s1[0];
    __syncthreads();

    float ls = 0.f;
    #pragma unroll
    for (int q = 0; q < 4; q++) {
        int j = base + q;
        if (j != r0) ls += __logf(f0[k0[q]]);
        if (j != r1) ls += __logf(f1[k1[q]]);
    }
    return ls;
}

__global__ __launch_bounds__(T3, 8) void lms_kernel(const __hip_bfloat16* __restrict__ E,
                                                    const float* __restrict__ theta,
                                                    const float* __restrict__ shift,
                                                    double* __restrict__ acc,
                                                    int rowBase) {
    __shared__ __align__(16) unsigned h0[NB2];   // 16 KB
    __shared__ __align__(16) unsigned h1[NB2];   // 16 KB
    __shared__ float wT0[NW], wT1[NW], wRed[NW];

    int tid = threadIdx.x;
    int lane = tid & 63;
    int wave = tid >> 6;
    int r0 = rowBase + 2 * blockIdx.x;
    int r1 = r0 + 1;

    // all six row-loads issued together: one latency exposure, E read once
    float4 tv0 = ((const float4*)&theta[(size_t)r0 * N])[tid];
    float4 tv1 = ((const float4*)&theta[(size_t)r1 * N])[tid];
    float4 sv0 = ((const float4*)&shift[(size_t)r0 * N])[tid];
    float4 sv1 = ((const float4*)&shift[(size_t)r1 * N])[tid];
    uint2 ea = ((const uint2*)&E[(size_t)r0 * N])[tid];
    uint2 eb = ((const uint2*)&E[(size_t)r1 * N])[tid];

    unsigned eu0[4], eu1[4], kT0[4], kT1[4], kS0[4], kS1[4];
    {
        unsigned e0b[4] = {ea.x << 16, ea.x & 0xffff0000u, ea.y << 16, ea.y & 0xffff0000u};
        unsigned e1b[4] = {eb.x << 16, eb.x & 0xffff0000u, eb.y << 16, eb.y & 0xffff0000u};
        float t0v[4] = {tv0.x, tv0.y, tv0.z, tv0.w};
        float t1v[4] = {tv1.x, tv1.y, tv1.z, tv1.w};
        float s0v[4] = {sv0.x, sv0.y, sv0.z, sv0.w};
        float s1v[4] = {sv1.x, sv1.y, sv1.z, sv1.w};
        const float ksT = (float)NB2 / 180.0f;
        const float ksS = (float)NB2 / 100.0f;
        #pragma unroll
        for (int q = 0; q < 4; q++) {
            eu0[q] = (unsigned)__float2uint_rn(__uint_as_float(e0b[q]) * ESCALE);
            eu1[q] = (unsigned)__float2uint_rn(__uint_as_float(e1b[q]) * ESCALE);
            kT0[q] = (unsigned)min(max((int)(t0v[q] * ksT), 0), NB2 - 1);
            kT1[q] = (unsigned)min(max((int)(t1v[q] * ksT), 0), NB2 - 1);
            kS0[q] = (unsigned)min(max((int)(s0v[q] * ksS), 0), NB2 - 1);
            kS1[q] = (unsigned)min(max((int)(s1v[q] * ksS), 0), NB2 - 1);
        }
    }

    float localSum = lms_pass2(kT0, kT1, eu0, eu1, h0, h1, wT0, wT1, tid, lane, wave, r0, r1)
                   + lms_pass2(kS0, kS1, eu0, eu1, h0, h1, wT0, wT1, tid, lane, wave, r0, r1);

    #pragma unroll
    for (int off = 32; off > 0; off >>= 1) localSum += __shfl_down(localSum, off);
    if (lane == 0) wRed[wave] = localSum;
    __syncthreads();
    if (tid == 0) {
        float s = 0.f;
        #pragma unroll
        for (int w = 0; w < NW; w++) s += wRed[w];
        atomicAdd(&acc[1], (double)s);
    }
}

// ---------------- final: combine ----------------
__global__ void final_kernel(const double* __restrict__ acc, float* __restrict__ out) {
    double denom = (double)N * (double)(N - 1);
    out[0] = (float)(-(acc[0] - 0.5 * acc[1]) / denom);
}

extern "C" void kernel_launch(void* const* d_in, const int* in_sizes, int n_in,
                              void* d_out, int out_size, void* d_ws, size_t ws_size,
                              hipStream_t stream) {
    const float* theta = (const float*)d_in[0];
    const float* shift = (const float*)d_in[1];
    const float* feat  = (const float*)d_in[2];
    float* out = (float*)d_out;

    char* ws = (char*)d_ws;
    double* acc = (double*)(ws + WS_ACC_OFF);
    float* x2 = (float*)(ws + WS_X2_OFF);

    bool big = ws_size >= WS_NEED_NEW;
    __hip_bfloat16* E = (__hip_bfloat16*)(ws + (big ? WS_E_NEW : WS_E_OLD));
    unsigned short* fbf = big ? (unsigned short*)(ws + WS_FBF_OFF) : nullptr;

    const int NTRI = (32 * 33) / 2;   // 528 lower-triangular 128x128 tiles

    hipMemsetAsync(acc, 0, 2 * sizeof(double), stream);
    x2_kernel<<<N, 64, 0, stream>>>(feat, x2, fbf);
    if (big)
        gram_tri<true><<<NTRI, 256, 0, stream>>>(fbf, feat, x2, E, acc);
    else
        gram_tri<false><<<NTRI, 256, 0, stream>>>(nullptr, feat, x2, E, acc);
    lms_kernel<<<N / 4, T3, 0, stream>>>(E, theta, shift, acc, 0);
    lms_kernel<<<N / 4, T3, 0, stream>>>(E, theta, shift, acc, N / 2);
    final_kernel<<<1, 1, 0, stream>>>(acc, out);
}